// Round 1
// baseline (1441.864 us; speedup 1.0000x reference)
//
#include <hip/hip_runtime.h>
#include <cstddef>

// ---------------------------------------------------------------------------
// Encoder, round 4: chunk-planar LDS layouts for conv_mfma.
//  - A halo and B weights stored plane-major ([16B-chunk][voxel/row][16B]) so
//    fragment ds_read_b128/b64 are bank-conflict-free (was 8/16-way at the old
//    64B voxel pitch). global_load_lds keeps a LINEAR LDS dest; the swizzle is
//    applied on the per-lane GLOBAL source address (m173 pattern).
//  - Occupancy bumped via templated __launch_bounds__ (conv3b: 40960B LDS ->
//    4 blocks/CU exactly).
// ---------------------------------------------------------------------------

#define EPSV 1e-5f

typedef _Float16 f16x4 __attribute__((ext_vector_type(4)));
typedef _Float16 f16x8 __attribute__((ext_vector_type(8)));
typedef float f32x4 __attribute__((ext_vector_type(4)));

template <int KC> struct FragSel;
template <> struct FragSel<32> { using T = f16x8; };
template <> struct FragSel<16> { using T = f16x4; };

__device__ __forceinline__ f32x4 mfma16(f16x8 a, f16x8 b, f32x4 c) {
    return __builtin_amdgcn_mfma_f32_16x16x32_f16(a, b, c, 0, 0, 0);
}
__device__ __forceinline__ f32x4 mfma16(f16x4 a, f16x4 b, f32x4 c) {
    return __builtin_amdgcn_mfma_f32_16x16x16f16(a, b, c, 0, 0, 0);
}

// async global->LDS, 16B per lane; LDS dest = wave-uniform base + lane*16
__device__ __forceinline__ void gld16(const void* g, void* l) {
    __builtin_amdgcn_global_load_lds(
        (const __attribute__((address_space(1))) unsigned int*)g,
        (__attribute__((address_space(3))) unsigned int*)l, 16, 0, 0);
}

// ---------------- mask pooling ----------------
__global__ __launch_bounds__(256) void pool0_kernel(const int* __restrict__ mask,
                                                    float* __restrict__ mout) {
    int voxel = blockIdx.x * 256 + threadIdx.x;          // 4 * 64^3
    int wo = voxel & 63, ho = (voxel >> 6) & 63, dd = (voxel >> 12) & 63, b = voxel >> 18;
    int any = 0;
#pragma unroll
    for (int dz = 0; dz < 2; ++dz)
#pragma unroll
        for (int hy = 0; hy < 2; ++hy)
#pragma unroll
            for (int wx = 0; wx < 2; ++wx) {
                size_t idx = ((size_t)((b * 128 + 2 * dd + dz) * 128 + 2 * ho + hy)) * 128
                             + 2 * wo + wx;
                any |= mask[idx];
            }
    mout[voxel] = any ? 1.f : 0.f;
}

__global__ __launch_bounds__(256) void poolf_kernel(const float* __restrict__ min_,
                                                    float* __restrict__ mout,
                                                    int Nout, int lnout) {
    int voxel = blockIdx.x * 256 + threadIdx.x;
    int Nin = Nout * 2;
    int wo = voxel & (Nout - 1);
    int ho = (voxel >> lnout) & (Nout - 1);
    int dd = (voxel >> (2 * lnout)) & (Nout - 1);
    int b = voxel >> (3 * lnout);
    float mx = 0.f;
#pragma unroll
    for (int dz = 0; dz < 2; ++dz)
#pragma unroll
        for (int hy = 0; hy < 2; ++hy)
#pragma unroll
            for (int wx = 0; wx < 2; ++wx) {
                size_t idx = ((size_t)((b * Nin + 2 * dd + dz) * Nin + 2 * ho + hy)) * Nin
                             + 2 * wo + wx;
                mx = fmaxf(mx, min_[idx]);
            }
    mout[voxel] = mx;
}

// ---------------- mask counts ----------------
__global__ __launch_bounds__(256) void mask_count_kernel(const float* __restrict__ m,
                                                         int nper, int blocks_per_batch,
                                                         float* __restrict__ cnt_total,
                                                         float* __restrict__ cnt_batch) {
    int batch = blockIdx.x / blocks_per_batch;
    int off = (blockIdx.x % blocks_per_batch) * 1024;
    float s = 0.f;
    for (int i = threadIdx.x; i < 1024; i += 256)
        s += m[(size_t)batch * nper + off + i];
    __shared__ float red[256];
    red[threadIdx.x] = s;
    __syncthreads();
    for (int st = 128; st > 0; st >>= 1) {
        if (threadIdx.x < st) red[threadIdx.x] += red[threadIdx.x + st];
        __syncthreads();
    }
    if (threadIdx.x == 0) {
        atomicAdd(cnt_total, red[0]);
        if (cnt_batch) atomicAdd(&cnt_batch[batch], red[0]);
    }
}

// ---------------- weight transform: [27][CIN][COUT] f32 -> [27][COUT][CIN] f16
__global__ __launch_bounds__(256) void wtrans_kernel(const float* __restrict__ w,
                                                     _Float16* __restrict__ o,
                                                     int CIN, int COUT, int total) {
    int i = blockIdx.x * 256 + threadIdx.x;
    if (i >= total) return;
    int co = i % COUT;
    int rest = i / COUT;
    int ci = rest % CIN;
    int t = rest / CIN;
    o[((size_t)(t * COUT + co)) * CIN + ci] = (_Float16)w[i];
}

// ---------------- conv1a: Cin=1, Cout=16, stride 2 (VALU) ----------
__global__ __launch_bounds__(256) void conv1a_kernel(const float* __restrict__ x,
                                                     const int* __restrict__ mask,
                                                     const float* __restrict__ w,
                                                     const float* __restrict__ m1,
                                                     _Float16* __restrict__ out) {
    int voxel = blockIdx.x * 256 + threadIdx.x;  // 4 * 64^3
    int wo = voxel & 63, ho = (voxel >> 6) & 63, dd = (voxel >> 12) & 63, b = voxel >> 18;
    float acc[16];
#pragma unroll
    for (int i = 0; i < 16; ++i) acc[i] = 0.f;
    for (int kd = 0; kd < 3; ++kd) {
        int id = 2 * dd + kd - 1;
        if ((unsigned)id >= 128u) continue;
        for (int kh = 0; kh < 3; ++kh) {
            int ih = 2 * ho + kh - 1;
            if ((unsigned)ih >= 128u) continue;
            for (int kw = 0; kw < 3; ++kw) {
                int iw = 2 * wo + kw - 1;
                if ((unsigned)iw >= 128u) continue;
                size_t idx = ((size_t)((b * 128 + id) * 128 + ih)) * 128 + iw;
                float xv = x[idx] * (float)mask[idx];
                const float* wp = w + ((kd * 3 + kh) * 3 + kw) * 16;
#pragma unroll
                for (int co = 0; co < 16; ++co) acc[co] = fmaf(xv, wp[co], acc[co]);
            }
        }
    }
    float m = m1[voxel];
    _Float16* op = out + (size_t)voxel * 16;
#pragma unroll
    for (int co = 0; co < 16; ++co) op[co] = (_Float16)(acc[co] * m);
}

// ---------------- unified MFMA implicit-GEMM conv (chunk-planar LDS) --------
// Block: 256 threads = 4 waves (WM in M x 4/WM in N). Output tile:
// M = TW*TH*TD voxels x NTILE couts.
// LDS layouts (16B "slot" = 8 halfs = one K-chunk of one MFMA quad):
//   halo: [plane p in 0..LPV)[voxel v in 0..HVP)  at (p*HVP+v)*16B
//   bbuf: [buf][plane p][row r in 0..NTILE)       at ((buf*LPV+p)*NTILE+r)*16B
// Fragment reads are therefore contiguous across the 16 lanes of a quad group
// (256B runs) -> conflict-free for stride-1 convs.
template <int CIN, int COUT, int NTILE, int STRIDE, int NIN, int NOUT,
          int TW, int LTW, int TH, int LTH, int TD, int WM, int MINW>
__global__ __launch_bounds__(256, MINW) void conv_mfma(const _Float16* __restrict__ in,
                                                       const _Float16* __restrict__ wt,
                                                       const float* __restrict__ mout,
                                                       _Float16* __restrict__ out,
                                                       const _Float16* __restrict__ zbuf) {
    constexpr int M = TW * TH * TD;
    constexpr int KC = (CIN >= 32) ? 32 : 16;
    constexpr int HW_ = (TW - 1) * STRIDE + 3;
    constexpr int HH_ = (TH - 1) * STRIDE + 3;
    constexpr int HD_ = (TD - 1) * STRIDE + 3;
    constexpr int HV = HW_ * HH_ * HD_;
    constexpr int LPV = (KC * 2) / 16;         // planes (16B chunks per voxel)
    constexpr int HVP = ((HV + 63) / 64) * 64; // padded voxels per plane
    constexpr int VBP = HVP / 64;              // halo stage insts per plane
    constexpr int AI = LPV * VBP;              // total halo stage insts
    constexpr int BSLOTS = LPV * NTILE;        // B 16B slots per tap
    constexpr int BI2 = (BSLOTS + 63) / 64;    // B stage insts per tap
    constexpr int LNT = __builtin_ctz(NTILE);
    constexpr int WN = 4 / WM;
    constexpr int WMT = M / WM;
    constexpr int WNT = NTILE / WN;
    constexpr int NAF = WMT / 16;
    constexpr int NBF = WNT / 16;
    constexpr int NBLK = COUT / NTILE;
    constexpr int NTW = NOUT / TW, NTH = NOUT / TH, NTD = NOUT / TD;
    constexpr int NUMM = 4 * NTW * NTH * NTD;

    using Frag = typename FragSel<KC>::T;

    __shared__ _Float16 halo[HVP * KC];         // LPV * HVP * 8 halfs
    __shared__ _Float16 bbuf[2 * NTILE * KC];   // 2 * LPV * NTILE * 8 halfs

    int bid = blockIdx.x;
    int nblk = (NBLK > 1) ? bid / NUMM : 0;
    int mblk = (NBLK > 1) ? bid % NUMM : bid;
    int tw = mblk % NTW;
    int th = (mblk / NTW) % NTH;
    int td = (mblk / (NTW * NTH)) % NTD;
    int b = mblk / (NTW * NTH * NTD);
    int d0 = td * TD * STRIDE - 1, h0 = th * TH * STRIDE - 1, w0 = tw * TW * STRIDE - 1;

    int tid = threadIdx.x;
    int wv = tid >> 6, lane = tid & 63, m16 = lane & 15, quad = lane >> 4;
    int wm_ = wv % WM, wn_ = wv / WM;
    // quad -> (plane, sub-offset in halfs) of the MFMA K-chunk
    int qp = (KC == 32) ? quad : (quad >> 1);
    int qs = (KC == 32) ? 0 : ((quad & 1) * 4);

    // A fragment LDS offsets (halfs), minus the per-tap voxel shift
    int aoff[NAF];
#pragma unroll
    for (int r = 0; r < NAF; ++r) {
        int vloc = wm_ * WMT + r * 16 + m16;
        int vw = vloc & (TW - 1), vh = (vloc >> LTW) & (TH - 1), vd = vloc >> (LTW + LTH);
        int avox = ((vd * STRIDE) * HH_ + vh * STRIDE) * HW_ + vw * STRIDE;
        aoff[r] = (qp * HVP + avox) * 8 + qs;
    }
    // B fragment LDS offsets (halfs) within one buffer
    int boff[NBF];
#pragma unroll
    for (int f = 0; f < NBF; ++f) {
        int row = wn_ * WNT + f * 16 + m16;
        boff[f] = (qp * NTILE + row) * 8 + qs;
    }

    f32x4 acc[NAF][NBF];
#pragma unroll
    for (int r = 0; r < NAF; ++r)
#pragma unroll
        for (int f = 0; f < NBF; ++f) acc[r][f] = (f32x4){0.f, 0.f, 0.f, 0.f};

    // stage halo: inst i writes 64 slots (1024B linear) of plane p, voxels
    // [vblk*64, vblk*64+64); lane's GLOBAL address carries the (v,p) mapping.
    auto stage_halo = [&](int c0) {
        for (int i = wv; i < AI; i += 4) {
            int p = i / VBP, vblk = i - p * VBP;
            int hv = vblk * 64 + lane;
            int hw = hv % HW_;
            int t2 = hv / HW_;
            int hh = t2 % HH_;
            int hd = t2 / HH_;
            int d = d0 + hd, h = h0 + hh, w = w0 + hw;
            bool ok = (hv < HV) && ((unsigned)d < (unsigned)NIN) &&
                      ((unsigned)h < (unsigned)NIN) && ((unsigned)w < (unsigned)NIN);
            const _Float16* g =
                ok ? in + ((size_t)(((b * NIN + d) * NIN + h) * NIN + w)) * CIN + c0 + p * 8
                   : zbuf;
            gld16(g, &halo[(p * HVP + vblk * 64) * 8]);
        }
    };

    // stage B tile for one tap: inst i writes slots [i*64, i*64+64);
    // slot s = p*NTILE + row.
    auto stage_B = [&](int tap, int buf, int c0) {
        const _Float16* wb = wt + (size_t)tap * COUT * CIN + (size_t)nblk * NTILE * CIN + c0;
        for (int i = wv; i < BI2; i += 4) {
            int s = i * 64 + lane;
            int p = s >> LNT;
            int row = s & (NTILE - 1);
            if ((BSLOTS & 63) == 0 || s < BSLOTS)
                gld16(wb + (size_t)row * CIN + p * 8, &bbuf[(buf * BSLOTS + i * 64) * 8]);
        }
    };

    for (int c0 = 0; c0 < CIN; c0 += KC) {
        __syncthreads();   // all reads of previous halo/B done
        stage_halo(c0);
        stage_B(0, 0, c0);
        int tap = 0;
        for (int kd = 0; kd < 3; ++kd)
            for (int kh = 0; kh < 3; ++kh)
                for (int kw = 0; kw < 3; ++kw, ++tap) {
                    __syncthreads();   // staged data for this tap visible
                    if (tap < 26) stage_B(tap + 1, (tap + 1) & 1, c0);
                    int tapv8 = ((kd * HH_ + kh) * HW_ + kw) * 8;
                    Frag a[NAF], bb[NBF];
#pragma unroll
                    for (int r = 0; r < NAF; ++r)
                        a[r] = *(const Frag*)&halo[aoff[r] + tapv8];
                    const _Float16* bp = &bbuf[(tap & 1) * (NTILE * KC)];
#pragma unroll
                    for (int f = 0; f < NBF; ++f) bb[f] = *(const Frag*)&bp[boff[f]];
#pragma unroll
                    for (int r = 0; r < NAF; ++r)
#pragma unroll
                        for (int f = 0; f < NBF; ++f)
                            acc[r][f] = mfma16(a[r], bb[f], acc[r][f]);
                }
    }

    // epilogue: C/D col = m16 (cout), row = quad*4 + j (voxel within frag)
    int n0 = nblk * NTILE + wn_ * WNT + m16;
#pragma unroll
    for (int r = 0; r < NAF; ++r) {
#pragma unroll
        for (int j = 0; j < 4; ++j) {
            int vloc = wm_ * WMT + r * 16 + quad * 4 + j;
            int vw = vloc & (TW - 1), vh = (vloc >> LTW) & (TH - 1), vd = vloc >> (LTW + LTH);
            int od = td * TD + vd, oh = th * TH + vh, ow = tw * TW + vw;
            size_t gvox = ((size_t)((b * NOUT + od) * NOUT + oh)) * NOUT + ow;
            float mv = mout[gvox];
            _Float16* op = out + gvox * COUT + n0;
#pragma unroll
            for (int f = 0; f < NBF; ++f) op[f * 16] = (_Float16)(acc[r][f][j] * mv);
        }
    }
}

// ---------------- BN stats: vectorized f16x8, per-channel sum/sumsq ---------
template <int C>
__global__ __launch_bounds__(256) void bn_stats_v(const _Float16* __restrict__ x,
                                                  long n, float* __restrict__ stats) {
    constexpr int G = C / 8;
    float s[8], q[8];
#pragma unroll
    for (int k = 0; k < 8; ++k) { s[k] = 0.f; q[k] = 0.f; }
    long stride = (long)gridDim.x * 2048;
    for (long i = ((long)blockIdx.x * 256 + threadIdx.x) * 8; i < n; i += stride) {
        f16x8 v = *(const f16x8*)(x + i);
#pragma unroll
        for (int k = 0; k < 8; ++k) {
            float f = (float)v[k];
            s[k] += f;
            q[k] += f * f;
        }
    }
    __shared__ float red[256 * 16];
#pragma unroll
    for (int k = 0; k < 8; ++k) {
        red[threadIdx.x * 16 + k] = s[k];
        red[threadIdx.x * 16 + 8 + k] = q[k];
    }
    __syncthreads();
    for (int st = 128; st >= G; st >>= 1) {
        if (threadIdx.x < st) {
#pragma unroll
            for (int k = 0; k < 16; ++k)
                red[threadIdx.x * 16 + k] += red[(threadIdx.x + st) * 16 + k];
        }
        __syncthreads();
    }
    if (threadIdx.x < G) {
        int cb = threadIdx.x * 8;
#pragma unroll
        for (int k = 0; k < 8; ++k) {
            atomicAdd(&stats[cb + k], red[threadIdx.x * 16 + k]);
            atomicAdd(&stats[C + cb + k], red[threadIdx.x * 16 + 8 + k]);
        }
    }
}

// ---------------- BN coef: scale/shift from stats ----------------
__global__ void bn_coef_kernel(const float* __restrict__ stats, const float* __restrict__ cnt,
                               const float* __restrict__ gamma, const float* __restrict__ beta,
                               float* __restrict__ coef, int C) {
    int c = threadIdx.x;
    if (c >= C) return;
    float cn = *cnt;
    float mean = stats[c] / cn;
    float var = stats[C + c] / cn - mean * mean;
    float sc = rsqrtf(var + EPSV) * gamma[c];
    coef[c] = sc;
    coef[C + c] = beta[c] - mean * sc;
}

// ---------------- BN apply + ELU + mask (vectorized) ----------------
template <int C, int LOGC>
__global__ __launch_bounds__(256) void bn_apply_v(_Float16* __restrict__ x,
                                                  const float* __restrict__ m,
                                                  const float* __restrict__ coef, long n) {
    long stride = (long)gridDim.x * 2048;
    for (long i8 = ((long)blockIdx.x * 256 + threadIdx.x) * 8; i8 < n; i8 += stride) {
        int c = (int)(i8 & (C - 1));
        long v = i8 >> LOGC;
        f16x8 xv = *(const f16x8*)(x + i8);
        float mv = m[v];
        f16x8 o;
#pragma unroll
        for (int k = 0; k < 8; ++k) {
            float xh = (float)xv[k] * coef[c + k] + coef[C + c + k];
            float e = xh > 0.f ? xh : expm1f(xh);
            o[k] = (_Float16)(e * mv);
        }
        *(f16x8*)(x + i8) = o;
    }
}

// ---------------- global masked mean pool (sums) ----------------
__global__ __launch_bounds__(256) void gpool_kernel(const _Float16* __restrict__ h,
                                                    float* __restrict__ pooled) {
    int b = blockIdx.x >> 3, seg = blockIdx.x & 7;  // 8 segments of 512 voxels
    int ch = (threadIdx.x & 63) * 8;
    int v0 = threadIdx.x >> 6;
    float s[8];
#pragma unroll
    for (int k = 0; k < 8; ++k) s[k] = 0.f;
    for (int v = v0; v < 512; v += 4) {
        const _Float16* p = h + ((size_t)(b * 4096 + seg * 512 + v)) * 512 + ch;
        f16x8 xv = *(const f16x8*)p;
#pragma unroll
        for (int k = 0; k < 8; ++k) s[k] += (float)xv[k];
    }
#pragma unroll
    for (int k = 0; k < 8; ++k) atomicAdd(&pooled[b * 512 + ch + k], s[k]);
}

// ---------------- heads ----------------
__global__ __launch_bounds__(256) void head_kernel(const float* __restrict__ pooled,
                                                   const float* __restrict__ cntb,
                                                   const float* __restrict__ wm,
                                                   const float* __restrict__ bm,
                                                   const float* __restrict__ wv,
                                                   const float* __restrict__ bv,
                                                   float* __restrict__ out) {
    int t = blockIdx.x * 256 + threadIdx.x;  // 4096
    int which = t >> 11;
    int b = (t >> 9) & 3;
    int j = t & 511;
    const float* W = which ? wv : wm;
    float bias = which ? bv[j] : bm[j];
    const float* p = pooled + b * 512;
    float s = 0.f;
    for (int c = 0; c < 512; ++c) s = fmaf(p[c], W[c * 512 + j], s);
    out[t] = s / cntb[b] + bias;
}

// ---------------------------------------------------------------------------
extern "C" void kernel_launch(void* const* d_in, const int* in_sizes, int n_in,
                              void* d_out, int out_size, void* d_ws, size_t ws_size,
                              hipStream_t stream) {
    const float* x   = (const float*)d_in[0];
    const int* mask  = (const int*)d_in[1];
    const float* w1a = (const float*)d_in[2];
    const float* g1a = (const float*)d_in[3];
    const float* b1a = (const float*)d_in[4];
    const float* w1b = (const float*)d_in[5];
    const float* g1b = (const float*)d_in[6];
    const float* b1b = (const float*)d_in[7];
    const float* w2a = (const float*)d_in[8];
    const float* g2a = (const float*)d_in[9];
    const float* b2a = (const float*)d_in[10];
    const float* w2b = (const float*)d_in[11];
    const float* g2b = (const float*)d_in[12];
    const float* b2b = (const float*)d_in[13];
    const float* w3a = (const float*)d_in[14];
    const float* g3a = (const float*)d_in[15];
    const float* b3a = (const float*)d_in[16];
    const float* w3b = (const float*)d_in[17];
    const float* g3b = (const float*)d_in[18];
    const float* b3b = (const float*)d_in[19];
    const float* wm  = (const float*)d_in[20];
    const float* bm  = (const float*)d_in[21];
    const float* wv  = (const float*)d_in[22];
    const float* bv  = (const float*)d_in[23];
    float* out = (float*)d_out;

    char* ws = (char*)d_ws;
    _Float16* A  = (_Float16*)(ws + 0);            // 32 MiB activations ping
    _Float16* Bb = (_Float16*)(ws + 33554432);     // 32 MiB activations pong
    _Float16* w1bh = (_Float16*)(ws + 67108864);   // 13,824 B (+pad for over-read)
    _Float16* w2ah = (_Float16*)(ws + 67125248);   // 55,296 B
    _Float16* w2bh = (_Float16*)(ws + 67182592);   // 221,184 B
    _Float16* w3ah = (_Float16*)(ws + 67403776);   // 1,769,472 B
    _Float16* w3bh = (_Float16*)(ws + 69173248);   // 14,155,776 B
    float* m1 = (float*)(ws + 83329024);           // 4 MiB
    float* m2 = (float*)(ws + 87523328);           // 512 KiB
    float* m3 = (float*)(ws + 88047616);           // 64 KiB
    float* stats  = (float*)(ws + 88113152);       // 4 KiB
    float* coef   = (float*)(ws + 88117248);       // 4 KiB
    float* counts = (float*)(ws + 88121344);       // 64 B
    float* pooled = (float*)(ws + 88121408);       // 8 KiB
    _Float16* zbuf = (_Float16*)(ws + 88129600);   // 256 B zeros

    _Float16* h1a = A;
    _Float16* h1b = Bb;
    _Float16* h2a = A;
    _Float16* h2b = Bb;
    _Float16* h3a = A;
    _Float16* h3b = Bb;

    hipMemsetAsync(counts, 0, 64 + 8192, stream);   // counts + pooled
    hipMemsetAsync(zbuf, 0, 256, stream);

    // masks + counts
    pool0_kernel<<<4096, 256, 0, stream>>>(mask, m1);
    poolf_kernel<<<512, 256, 0, stream>>>(m1, m2, 32, 5);
    poolf_kernel<<<64, 256, 0, stream>>>(m2, m3, 16, 4);
    mask_count_kernel<<<1024, 256, 0, stream>>>(m1, 262144, 256, counts + 0, nullptr);
    mask_count_kernel<<<128, 256, 0, stream>>>(m2, 32768, 32, counts + 1, nullptr);
    mask_count_kernel<<<16, 256, 0, stream>>>(m3, 4096, 4, counts + 2, counts + 4);

    // weight transforms (fp32 [27][CIN][COUT] -> fp16 [27][COUT][CIN])
    wtrans_kernel<<<(6912 + 255) / 256, 256, 0, stream>>>(w1b, w1bh, 16, 16, 6912);
    wtrans_kernel<<<(27648 + 255) / 256, 256, 0, stream>>>(w2a, w2ah, 16, 64, 27648);
    wtrans_kernel<<<(110592 + 255) / 256, 256, 0, stream>>>(w2b, w2bh, 64, 64, 110592);
    wtrans_kernel<<<(884736 + 255) / 256, 256, 0, stream>>>(w3a, w3ah, 64, 512, 884736);
    wtrans_kernel<<<(7077888 + 255) / 256, 256, 0, stream>>>(w3b, w3bh, 512, 512, 7077888);

    // ---- block 1 ----
    conv1a_kernel<<<4096, 256, 0, stream>>>(x, mask, w1a, m1, h1a);
    hipMemsetAsync(stats, 0, 4096, stream);
    bn_stats_v<16><<<512, 256, 0, stream>>>(h1a, 16777216L, stats);
    bn_coef_kernel<<<1, 512, 0, stream>>>(stats, counts + 0, g1a, b1a, coef, 16);
    bn_apply_v<16, 4><<<2048, 256, 0, stream>>>(h1a, m1, coef, 16777216L);

    conv_mfma<16, 16, 16, 1, 64, 64, 8, 3, 4, 2, 4, 4, 6>
        <<<8192, 256, 0, stream>>>(h1a, w1bh, m1, h1b, zbuf);
    hipMemsetAsync(stats, 0, 4096, stream);
    bn_stats_v<16><<<512, 256, 0, stream>>>(h1b, 16777216L, stats);
    bn_coef_kernel<<<1, 512, 0, stream>>>(stats, counts + 0, g1b, b1b, coef, 16);
    bn_apply_v<16, 4><<<2048, 256, 0, stream>>>(h1b, m1, coef, 16777216L);

    // ---- block 2 ----
    conv_mfma<16, 64, 64, 2, 64, 32, 4, 2, 4, 2, 4, 2, 4>
        <<<2048, 256, 0, stream>>>(h1b, w2ah, m2, h2a, zbuf);
    hipMemsetAsync(stats, 0, 4096, stream);
    bn_stats_v<64><<<256, 256, 0, stream>>>(h2a, 8388608L, stats);
    bn_coef_kernel<<<1, 512, 0, stream>>>(stats, counts + 1, g2a, b2a, coef, 64);
    bn_apply_v<64, 6><<<1024, 256, 0, stream>>>(h2a, m2, coef, 8388608L);

    conv_mfma<64, 64, 64, 1, 32, 32, 8, 3, 4, 2, 4, 2, 4>
        <<<1024, 256, 0, stream>>>(h2a, w2bh, m2, h2b, zbuf);
    hipMemsetAsync(stats, 0, 4096, stream);
    bn_stats_v<64><<<256, 256, 0, stream>>>(h2b, 8388608L, stats);
    bn_coef_kernel<<<1, 512, 0, stream>>>(stats, counts + 1, g2b, b2b, coef, 64);
    bn_apply_v<64, 6><<<1024, 256, 0, stream>>>(h2b, m2, coef, 8388608L);

    // ---- block 3 ----
    conv_mfma<64, 512, 128, 2, 32, 16, 4, 2, 4, 2, 4, 2, 2>
        <<<1024, 256, 0, stream>>>(h2b, w3ah, m3, h3a, zbuf);
    hipMemsetAsync(stats, 0, 4096, stream);
    bn_stats_v<512><<<128, 256, 0, stream>>>(h3a, 8388608L, stats);
    bn_coef_kernel<<<1, 512, 0, stream>>>(stats, counts + 2, g3a, b3a, coef, 512);
    bn_apply_v<512, 9><<<512, 256, 0, stream>>>(h3a, m3, coef, 8388608L);

    conv_mfma<512, 512, 128, 1, 16, 16, 8, 3, 4, 2, 4, 2, 4>
        <<<512, 256, 0, stream>>>(h3a, w3bh, m3, h3b, zbuf);
    hipMemsetAsync(stats, 0, 4096, stream);
    bn_stats_v<512><<<128, 256, 0, stream>>>(h3b, 8388608L, stats);
    bn_coef_kernel<<<1, 512, 0, stream>>>(stats, counts + 2, g3b, b3b, coef, 512);
    bn_apply_v<512, 9><<<512, 256, 0, stream>>>(h3b, m3, coef, 8388608L);

    // ---- pool + heads ----
    gpool_kernel<<<32, 256, 0, stream>>>(h3b, pooled);
    head_kernel<<<16, 256, 0, stream>>>(pooled, counts + 4, wm, bm, wv, bv, out);
}

// Round 2
// 1252.663 us; speedup vs baseline: 1.1510x; 1.1510x over previous
//
#include <hip/hip_runtime.h>
#include <cstddef>

// ---------------------------------------------------------------------------
// Encoder, round 5: round-3 structure + byte-XOR LDS swizzle (both sides).
//  - Voxel-major LDS (coalesced 64B-segment global staging, linear LDS dest).
//  - sigma(B) = B ^ (((B>>7)&7)<<4) applied to the global-source lane mapping
//    (staging) AND the fragment read offsets -> bank-balanced ds_read_b128/b64
//    for stride-1 AND stride-2 convs.
//  - XCD-chunked blockIdx swizzle on conv_mfma (weight slice per-XCD L2 fit).
// ---------------------------------------------------------------------------

#define EPSV 1e-5f

typedef _Float16 f16x4 __attribute__((ext_vector_type(4)));
typedef _Float16 f16x8 __attribute__((ext_vector_type(8)));
typedef float f32x4 __attribute__((ext_vector_type(4)));

template <int KC> struct FragSel;
template <> struct FragSel<32> { using T = f16x8; };
template <> struct FragSel<16> { using T = f16x4; };

__device__ __forceinline__ f32x4 mfma16(f16x8 a, f16x8 b, f32x4 c) {
    return __builtin_amdgcn_mfma_f32_16x16x32_f16(a, b, c, 0, 0, 0);
}
__device__ __forceinline__ f32x4 mfma16(f16x4 a, f16x4 b, f32x4 c) {
    return __builtin_amdgcn_mfma_f32_16x16x16f16(a, b, c, 0, 0, 0);
}

// async global->LDS, 16B per lane; LDS dest = wave-uniform base + lane*16
__device__ __forceinline__ void gld16(const void* g, void* l) {
    __builtin_amdgcn_global_load_lds(
        (const __attribute__((address_space(1))) unsigned int*)g,
        (__attribute__((address_space(3))) unsigned int*)l, 16, 0, 0);
}

// self-inverse byte-offset swizzle: XOR 16B-chunk bits [4:6] with bits [7:9]
__device__ __forceinline__ int swz(int b) { return b ^ ((b >> 3) & 0x70); }

// ---------------- mask pooling ----------------
__global__ __launch_bounds__(256) void pool0_kernel(const int* __restrict__ mask,
                                                    float* __restrict__ mout) {
    int voxel = blockIdx.x * 256 + threadIdx.x;          // 4 * 64^3
    int wo = voxel & 63, ho = (voxel >> 6) & 63, dd = (voxel >> 12) & 63, b = voxel >> 18;
    int any = 0;
#pragma unroll
    for (int dz = 0; dz < 2; ++dz)
#pragma unroll
        for (int hy = 0; hy < 2; ++hy)
#pragma unroll
            for (int wx = 0; wx < 2; ++wx) {
                size_t idx = ((size_t)((b * 128 + 2 * dd + dz) * 128 + 2 * ho + hy)) * 128
                             + 2 * wo + wx;
                any |= mask[idx];
            }
    mout[voxel] = any ? 1.f : 0.f;
}

__global__ __launch_bounds__(256) void poolf_kernel(const float* __restrict__ min_,
                                                    float* __restrict__ mout,
                                                    int Nout, int lnout) {
    int voxel = blockIdx.x * 256 + threadIdx.x;
    int Nin = Nout * 2;
    int wo = voxel & (Nout - 1);
    int ho = (voxel >> lnout) & (Nout - 1);
    int dd = (voxel >> (2 * lnout)) & (Nout - 1);
    int b = voxel >> (3 * lnout);
    float mx = 0.f;
#pragma unroll
    for (int dz = 0; dz < 2; ++dz)
#pragma unroll
        for (int hy = 0; hy < 2; ++hy)
#pragma unroll
            for (int wx = 0; wx < 2; ++wx) {
                size_t idx = ((size_t)((b * Nin + 2 * dd + dz) * Nin + 2 * ho + hy)) * Nin
                             + 2 * wo + wx;
                mx = fmaxf(mx, min_[idx]);
            }
    mout[voxel] = mx;
}

// ---------------- mask counts ----------------
__global__ __launch_bounds__(256) void mask_count_kernel(const float* __restrict__ m,
                                                         int nper, int blocks_per_batch,
                                                         float* __restrict__ cnt_total,
                                                         float* __restrict__ cnt_batch) {
    int batch = blockIdx.x / blocks_per_batch;
    int off = (blockIdx.x % blocks_per_batch) * 1024;
    float s = 0.f;
    for (int i = threadIdx.x; i < 1024; i += 256)
        s += m[(size_t)batch * nper + off + i];
    __shared__ float red[256];
    red[threadIdx.x] = s;
    __syncthreads();
    for (int st = 128; st > 0; st >>= 1) {
        if (threadIdx.x < st) red[threadIdx.x] += red[threadIdx.x + st];
        __syncthreads();
    }
    if (threadIdx.x == 0) {
        atomicAdd(cnt_total, red[0]);
        if (cnt_batch) atomicAdd(&cnt_batch[batch], red[0]);
    }
}

// ---------------- weight transform: [27][CIN][COUT] f32 -> [27][COUT][CIN] f16
__global__ __launch_bounds__(256) void wtrans_kernel(const float* __restrict__ w,
                                                     _Float16* __restrict__ o,
                                                     int CIN, int COUT, int total) {
    int i = blockIdx.x * 256 + threadIdx.x;
    if (i >= total) return;
    int co = i % COUT;
    int rest = i / COUT;
    int ci = rest % CIN;
    int t = rest / CIN;
    o[((size_t)(t * COUT + co)) * CIN + ci] = (_Float16)w[i];
}

// ---------------- conv1a: Cin=1, Cout=16, stride 2 (VALU) ----------
__global__ __launch_bounds__(256) void conv1a_kernel(const float* __restrict__ x,
                                                     const int* __restrict__ mask,
                                                     const float* __restrict__ w,
                                                     const float* __restrict__ m1,
                                                     _Float16* __restrict__ out) {
    int voxel = blockIdx.x * 256 + threadIdx.x;  // 4 * 64^3
    int wo = voxel & 63, ho = (voxel >> 6) & 63, dd = (voxel >> 12) & 63, b = voxel >> 18;
    float acc[16];
#pragma unroll
    for (int i = 0; i < 16; ++i) acc[i] = 0.f;
    for (int kd = 0; kd < 3; ++kd) {
        int id = 2 * dd + kd - 1;
        if ((unsigned)id >= 128u) continue;
        for (int kh = 0; kh < 3; ++kh) {
            int ih = 2 * ho + kh - 1;
            if ((unsigned)ih >= 128u) continue;
            for (int kw = 0; kw < 3; ++kw) {
                int iw = 2 * wo + kw - 1;
                if ((unsigned)iw >= 128u) continue;
                size_t idx = ((size_t)((b * 128 + id) * 128 + ih)) * 128 + iw;
                float xv = x[idx] * (float)mask[idx];
                const float* wp = w + ((kd * 3 + kh) * 3 + kw) * 16;
#pragma unroll
                for (int co = 0; co < 16; ++co) acc[co] = fmaf(xv, wp[co], acc[co]);
            }
        }
    }
    float m = m1[voxel];
    _Float16* op = out + (size_t)voxel * 16;
#pragma unroll
    for (int co = 0; co < 16; ++co) op[co] = (_Float16)(acc[co] * m);
}

// ---------------- unified MFMA implicit-GEMM conv ----------------
// Block: 256 threads = 4 waves (WM in M x 4/WM in N). Output tile:
// M = TW*TH*TD voxels x NTILE couts. Voxel-major LDS (KB bytes/voxel),
// swizzled by sigma on BOTH the staging source mapping and the frag reads.
template <int CIN, int COUT, int NTILE, int STRIDE, int NIN, int NOUT,
          int TW, int LTW, int TH, int LTH, int TD, int WM>
__global__ __launch_bounds__(256, 2) void conv_mfma(const _Float16* __restrict__ in,
                                                    const _Float16* __restrict__ wt,
                                                    const float* __restrict__ mout,
                                                    _Float16* __restrict__ out,
                                                    const _Float16* __restrict__ zbuf) {
    constexpr int M = TW * TH * TD;
    constexpr int KC = (CIN >= 32) ? 32 : 16;
    constexpr int KB = KC * 2;                 // bytes per voxel per K-chunk
    constexpr int LKB = (KC >= 32) ? 6 : 5;    // log2(KB)
    constexpr int HW_ = (TW - 1) * STRIDE + 3;
    constexpr int HH_ = (TH - 1) * STRIDE + 3;
    constexpr int HD_ = (TD - 1) * STRIDE + 3;
    constexpr int HV = HW_ * HH_ * HD_;
    constexpr int LPV = KB / 16;               // 16B chunks per voxel (4 or 2)
    constexpr int VPI = 64 / LPV;              // voxels per stage inst
    constexpr int NIH = (HV + VPI - 1) / VPI;
    constexpr int HVP = NIH * VPI;
    constexpr int WN = 4 / WM;
    constexpr int WMT = M / WM;
    constexpr int WNT = NTILE / WN;
    constexpr int NAF = WMT / 16;
    constexpr int NBF = WNT / 16;
    constexpr int NBLK = COUT / NTILE;
    constexpr int NTW = NOUT / TW, NTH = NOUT / TH, NTD = NOUT / TD;
    constexpr int NUMM = 4 * NTW * NTH * NTD;
    constexpr int BI = (NTILE * KB + 1023) / 1024;  // B stage insts per tap

    using Frag = typename FragSel<KC>::T;

    __shared__ _Float16 halo[HVP * KC];
    __shared__ _Float16 bbuf[2 * NTILE * KC];

    // XCD-chunked block swizzle (all grids are multiples of 8)
    int cpx = gridDim.x >> 3;
    int bid = (blockIdx.x & 7) * cpx + (blockIdx.x >> 3);

    int nblk = (NBLK > 1) ? bid / NUMM : 0;
    int mblk = (NBLK > 1) ? bid % NUMM : bid;
    int tw = mblk % NTW;
    int th = (mblk / NTW) % NTH;
    int td = (mblk / (NTW * NTH)) % NTD;
    int b = mblk / (NTW * NTH * NTD);
    int d0 = td * TD * STRIDE - 1, h0 = th * TH * STRIDE - 1, w0 = tw * TW * STRIDE - 1;

    int tid = threadIdx.x;
    int wv = tid >> 6, lane = tid & 63, m16 = lane & 15, quad = lane >> 4;
    int wm_ = wv % WM, wn_ = wv / WM;
    int qb = quad * (KB / 4);   // quad's 16B(8B) chunk byte offset within voxel

    // A fragment voxel bases (per-tap shift added at read time, then swizzled)
    int abase[NAF];
#pragma unroll
    for (int r = 0; r < NAF; ++r) {
        int vloc = wm_ * WMT + r * 16 + m16;
        int vw = vloc & (TW - 1), vh = (vloc >> LTW) & (TH - 1), vd = vloc >> (LTW + LTH);
        abase[r] = ((vd * STRIDE) * HH_ + vh * STRIDE) * HW_ + vw * STRIDE;
    }
    // B fragment swizzled byte offsets (constant; relative to buffer base)
    int bofsw[NBF];
#pragma unroll
    for (int f = 0; f < NBF; ++f)
        bofsw[f] = swz((wn_ * WNT + f * 16 + m16) * KB + qb);

    f32x4 acc[NAF][NBF];
#pragma unroll
    for (int r = 0; r < NAF; ++r)
#pragma unroll
        for (int f = 0; f < NBF; ++f) acc[r][f] = (f32x4){0.f, 0.f, 0.f, 0.f};

    // stage halo: inst i writes LDS bytes [i*1024, +1024) linearly; lane's
    // global source is the sigma-inverse of its slot -> coalesced 64B segments.
    auto stage_halo = [&](int c0) {
        for (int i = wv; i < NIH; i += 4) {
            int S = i * 1024 + lane * 16;
            int Bq = swz(S);
            int hv = Bq >> LKB;
            int cb = Bq & (KB - 1);   // chunk byte offset within voxel
            int hw = hv % HW_;
            int t2 = hv / HW_;
            int hh = t2 % HH_;
            int hd = t2 / HH_;
            int d = d0 + hd, h = h0 + hh, w = w0 + hw;
            bool ok = (hv < HV) && ((unsigned)d < (unsigned)NIN) &&
                      ((unsigned)h < (unsigned)NIN) && ((unsigned)w < (unsigned)NIN);
            const _Float16* g =
                ok ? in + ((size_t)(((b * NIN + d) * NIN + h) * NIN + w)) * CIN + c0 + (cb >> 1)
                   : zbuf;
            gld16(g, (char*)halo + i * 1024);
        }
    };

    // stage B tile for one tap (same sigma-inverse source mapping)
    auto stage_B = [&](int tap, int buf, int c0) {
        const _Float16* wb = wt + (size_t)tap * COUT * CIN + (size_t)nblk * NTILE * CIN + c0;
        for (int i = wv; i < BI; i += 4) {
            int S = i * 1024 + lane * 16;
            int Bq = swz(S);
            int row = Bq >> LKB;
            int cb = Bq & (KB - 1);
            if ((NTILE * KB) % 1024 == 0 || row < NTILE)
                gld16(wb + (size_t)row * CIN + (cb >> 1),
                      (char*)bbuf + buf * (NTILE * KB) + i * 1024);
        }
    };

    for (int c0 = 0; c0 < CIN; c0 += KC) {
        __syncthreads();   // all reads of previous halo/B done
        stage_halo(c0);
        stage_B(0, 0, c0);
        for (int t = 0; t < 27; ++t) {
            __syncthreads();   // staged data for tap t visible
            if (t < 26) stage_B(t + 1, (t + 1) & 1, c0);
            int tapv = ((t / 9) * HH_ + ((t % 9) / 3)) * HW_ + (t % 3);
            Frag a[NAF], bb[NBF];
#pragma unroll
            for (int r = 0; r < NAF; ++r)
                a[r] = *(const Frag*)((const char*)halo + swz((abase[r] + tapv) * KB + qb));
            const char* bp = (const char*)bbuf + (t & 1) * (NTILE * KB);
#pragma unroll
            for (int f = 0; f < NBF; ++f) bb[f] = *(const Frag*)(bp + bofsw[f]);
#pragma unroll
            for (int r = 0; r < NAF; ++r)
#pragma unroll
                for (int f = 0; f < NBF; ++f) acc[r][f] = mfma16(a[r], bb[f], acc[r][f]);
        }
    }

    // epilogue: C/D col = m16 (cout), row = quad*4 + j (voxel within frag)
    int n0 = nblk * NTILE + wn_ * WNT + m16;
#pragma unroll
    for (int r = 0; r < NAF; ++r) {
#pragma unroll
        for (int j = 0; j < 4; ++j) {
            int vloc = wm_ * WMT + r * 16 + quad * 4 + j;
            int vw = vloc & (TW - 1), vh = (vloc >> LTW) & (TH - 1), vd = vloc >> (LTW + LTH);
            int od = td * TD + vd, oh = th * TH + vh, ow = tw * TW + vw;
            size_t gvox = ((size_t)((b * NOUT + od) * NOUT + oh)) * NOUT + ow;
            float mv = mout[gvox];
            _Float16* op = out + gvox * COUT + n0;
#pragma unroll
            for (int f = 0; f < NBF; ++f) op[f * 16] = (_Float16)(acc[r][f][j] * mv);
        }
    }
}

// ---------------- BN stats: vectorized f16x8, per-channel sum/sumsq ---------
template <int C>
__global__ __launch_bounds__(256) void bn_stats_v(const _Float16* __restrict__ x,
                                                  long n, float* __restrict__ stats) {
    constexpr int G = C / 8;
    float s[8], q[8];
#pragma unroll
    for (int k = 0; k < 8; ++k) { s[k] = 0.f; q[k] = 0.f; }
    long stride = (long)gridDim.x * 2048;
    for (long i = ((long)blockIdx.x * 256 + threadIdx.x) * 8; i < n; i += stride) {
        f16x8 v = *(const f16x8*)(x + i);
#pragma unroll
        for (int k = 0; k < 8; ++k) {
            float f = (float)v[k];
            s[k] += f;
            q[k] += f * f;
        }
    }
    __shared__ float red[256 * 16];
#pragma unroll
    for (int k = 0; k < 8; ++k) {
        red[threadIdx.x * 16 + k] = s[k];
        red[threadIdx.x * 16 + 8 + k] = q[k];
    }
    __syncthreads();
    for (int st = 128; st >= G; st >>= 1) {
        if (threadIdx.x < st) {
#pragma unroll
            for (int k = 0; k < 16; ++k)
                red[threadIdx.x * 16 + k] += red[(threadIdx.x + st) * 16 + k];
        }
        __syncthreads();
    }
    if (threadIdx.x < G) {
        int cb = threadIdx.x * 8;
#pragma unroll
        for (int k = 0; k < 8; ++k) {
            atomicAdd(&stats[cb + k], red[threadIdx.x * 16 + k]);
            atomicAdd(&stats[C + cb + k], red[threadIdx.x * 16 + 8 + k]);
        }
    }
}

// ---------------- BN coef: scale/shift from stats ----------------
__global__ void bn_coef_kernel(const float* __restrict__ stats, const float* __restrict__ cnt,
                               const float* __restrict__ gamma, const float* __restrict__ beta,
                               float* __restrict__ coef, int C) {
    int c = threadIdx.x;
    if (c >= C) return;
    float cn = *cnt;
    float mean = stats[c] / cn;
    float var = stats[C + c] / cn - mean * mean;
    float sc = rsqrtf(var + EPSV) * gamma[c];
    coef[c] = sc;
    coef[C + c] = beta[c] - mean * sc;
}

// ---------------- BN apply + ELU + mask (vectorized) ----------------
template <int C, int LOGC>
__global__ __launch_bounds__(256) void bn_apply_v(_Float16* __restrict__ x,
                                                  const float* __restrict__ m,
                                                  const float* __restrict__ coef, long n) {
    long stride = (long)gridDim.x * 2048;
    for (long i8 = ((long)blockIdx.x * 256 + threadIdx.x) * 8; i8 < n; i8 += stride) {
        int c = (int)(i8 & (C - 1));
        long v = i8 >> LOGC;
        f16x8 xv = *(const f16x8*)(x + i8);
        float mv = m[v];
        f16x8 o;
#pragma unroll
        for (int k = 0; k < 8; ++k) {
            float xh = (float)xv[k] * coef[c + k] + coef[C + c + k];
            float e = xh > 0.f ? xh : expm1f(xh);
            o[k] = (_Float16)(e * mv);
        }
        *(f16x8*)(x + i8) = o;
    }
}

// ---------------- global masked mean pool (sums) ----------------
__global__ __launch_bounds__(256) void gpool_kernel(const _Float16* __restrict__ h,
                                                    float* __restrict__ pooled) {
    int b = blockIdx.x >> 3, seg = blockIdx.x & 7;  // 8 segments of 512 voxels
    int ch = (threadIdx.x & 63) * 8;
    int v0 = threadIdx.x >> 6;
    float s[8];
#pragma unroll
    for (int k = 0; k < 8; ++k) s[k] = 0.f;
    for (int v = v0; v < 512; v += 4) {
        const _Float16* p = h + ((size_t)(b * 4096 + seg * 512 + v)) * 512 + ch;
        f16x8 xv = *(const f16x8*)p;
#pragma unroll
        for (int k = 0; k < 8; ++k) s[k] += (float)xv[k];
    }
#pragma unroll
    for (int k = 0; k < 8; ++k) atomicAdd(&pooled[b * 512 + ch + k], s[k]);
}

// ---------------- heads ----------------
__global__ __launch_bounds__(256) void head_kernel(const float* __restrict__ pooled,
                                                   const float* __restrict__ cntb,
                                                   const float* __restrict__ wm,
                                                   const float* __restrict__ bm,
                                                   const float* __restrict__ wv,
                                                   const float* __restrict__ bv,
                                                   float* __restrict__ out) {
    int t = blockIdx.x * 256 + threadIdx.x;  // 4096
    int which = t >> 11;
    int b = (t >> 9) & 3;
    int j = t & 511;
    const float* W = which ? wv : wm;
    float bias = which ? bv[j] : bm[j];
    const float* p = pooled + b * 512;
    float s = 0.f;
    for (int c = 0; c < 512; ++c) s = fmaf(p[c], W[c * 512 + j], s);
    out[t] = s / cntb[b] + bias;
}

// ---------------------------------------------------------------------------
extern "C" void kernel_launch(void* const* d_in, const int* in_sizes, int n_in,
                              void* d_out, int out_size, void* d_ws, size_t ws_size,
                              hipStream_t stream) {
    const float* x   = (const float*)d_in[0];
    const int* mask  = (const int*)d_in[1];
    const float* w1a = (const float*)d_in[2];
    const float* g1a = (const float*)d_in[3];
    const float* b1a = (const float*)d_in[4];
    const float* w1b = (const float*)d_in[5];
    const float* g1b = (const float*)d_in[6];
    const float* b1b = (const float*)d_in[7];
    const float* w2a = (const float*)d_in[8];
    const float* g2a = (const float*)d_in[9];
    const float* b2a = (const float*)d_in[10];
    const float* w2b = (const float*)d_in[11];
    const float* g2b = (const float*)d_in[12];
    const float* b2b = (const float*)d_in[13];
    const float* w3a = (const float*)d_in[14];
    const float* g3a = (const float*)d_in[15];
    const float* b3a = (const float*)d_in[16];
    const float* w3b = (const float*)d_in[17];
    const float* g3b = (const float*)d_in[18];
    const float* b3b = (const float*)d_in[19];
    const float* wm  = (const float*)d_in[20];
    const float* bm  = (const float*)d_in[21];
    const float* wv  = (const float*)d_in[22];
    const float* bv  = (const float*)d_in[23];
    float* out = (float*)d_out;

    char* ws = (char*)d_ws;
    _Float16* A  = (_Float16*)(ws + 0);            // 32 MiB activations ping
    _Float16* Bb = (_Float16*)(ws + 33554432);     // 32 MiB activations pong
    _Float16* w1bh = (_Float16*)(ws + 67108864);   // 13,824 B (+pad for over-read)
    _Float16* w2ah = (_Float16*)(ws + 67125248);   // 55,296 B
    _Float16* w2bh = (_Float16*)(ws + 67182592);   // 221,184 B
    _Float16* w3ah = (_Float16*)(ws + 67403776);   // 1,769,472 B
    _Float16* w3bh = (_Float16*)(ws + 69173248);   // 14,155,776 B
    float* m1 = (float*)(ws + 83329024);           // 4 MiB
    float* m2 = (float*)(ws + 87523328);           // 512 KiB
    float* m3 = (float*)(ws + 88047616);           // 64 KiB
    float* stats  = (float*)(ws + 88113152);       // 4 KiB
    float* coef   = (float*)(ws + 88117248);       // 4 KiB
    float* counts = (float*)(ws + 88121344);       // 64 B
    float* pooled = (float*)(ws + 88121408);       // 8 KiB
    _Float16* zbuf = (_Float16*)(ws + 88129600);   // 256 B zeros

    _Float16* h1a = A;
    _Float16* h1b = Bb;
    _Float16* h2a = A;
    _Float16* h2b = Bb;
    _Float16* h3a = A;
    _Float16* h3b = Bb;

    hipMemsetAsync(counts, 0, 64 + 8192, stream);   // counts + pooled
    hipMemsetAsync(zbuf, 0, 256, stream);

    // masks + counts
    pool0_kernel<<<4096, 256, 0, stream>>>(mask, m1);
    poolf_kernel<<<512, 256, 0, stream>>>(m1, m2, 32, 5);
    poolf_kernel<<<64, 256, 0, stream>>>(m2, m3, 16, 4);
    mask_count_kernel<<<1024, 256, 0, stream>>>(m1, 262144, 256, counts + 0, nullptr);
    mask_count_kernel<<<128, 256, 0, stream>>>(m2, 32768, 32, counts + 1, nullptr);
    mask_count_kernel<<<16, 256, 0, stream>>>(m3, 4096, 4, counts + 2, counts + 4);

    // weight transforms (fp32 [27][CIN][COUT] -> fp16 [27][COUT][CIN])
    wtrans_kernel<<<(6912 + 255) / 256, 256, 0, stream>>>(w1b, w1bh, 16, 16, 6912);
    wtrans_kernel<<<(27648 + 255) / 256, 256, 0, stream>>>(w2a, w2ah, 16, 64, 27648);
    wtrans_kernel<<<(110592 + 255) / 256, 256, 0, stream>>>(w2b, w2bh, 64, 64, 110592);
    wtrans_kernel<<<(884736 + 255) / 256, 256, 0, stream>>>(w3a, w3ah, 64, 512, 884736);
    wtrans_kernel<<<(7077888 + 255) / 256, 256, 0, stream>>>(w3b, w3bh, 512, 512, 7077888);

    // ---- block 1 ----
    conv1a_kernel<<<4096, 256, 0, stream>>>(x, mask, w1a, m1, h1a);
    hipMemsetAsync(stats, 0, 4096, stream);
    bn_stats_v<16><<<512, 256, 0, stream>>>(h1a, 16777216L, stats);
    bn_coef_kernel<<<1, 512, 0, stream>>>(stats, counts + 0, g1a, b1a, coef, 16);
    bn_apply_v<16, 4><<<2048, 256, 0, stream>>>(h1a, m1, coef, 16777216L);

    conv_mfma<16, 16, 16, 1, 64, 64, 8, 3, 4, 2, 4, 4>
        <<<8192, 256, 0, stream>>>(h1a, w1bh, m1, h1b, zbuf);
    hipMemsetAsync(stats, 0, 4096, stream);
    bn_stats_v<16><<<512, 256, 0, stream>>>(h1b, 16777216L, stats);
    bn_coef_kernel<<<1, 512, 0, stream>>>(stats, counts + 0, g1b, b1b, coef, 16);
    bn_apply_v<16, 4><<<2048, 256, 0, stream>>>(h1b, m1, coef, 16777216L);

    // ---- block 2 ----
    conv_mfma<16, 64, 64, 2, 64, 32, 4, 2, 4, 2, 4, 2>
        <<<2048, 256, 0, stream>>>(h1b, w2ah, m2, h2a, zbuf);
    hipMemsetAsync(stats, 0, 4096, stream);
    bn_stats_v<64><<<256, 256, 0, stream>>>(h2a, 8388608L, stats);
    bn_coef_kernel<<<1, 512, 0, stream>>>(stats, counts + 1, g2a, b2a, coef, 64);
    bn_apply_v<64, 6><<<1024, 256, 0, stream>>>(h2a, m2, coef, 8388608L);

    conv_mfma<64, 64, 64, 1, 32, 32, 8, 3, 4, 2, 4, 2>
        <<<1024, 256, 0, stream>>>(h2a, w2bh, m2, h2b, zbuf);
    hipMemsetAsync(stats, 0, 4096, stream);
    bn_stats_v<64><<<256, 256, 0, stream>>>(h2b, 8388608L, stats);
    bn_coef_kernel<<<1, 512, 0, stream>>>(stats, counts + 1, g2b, b2b, coef, 64);
    bn_apply_v<64, 6><<<1024, 256, 0, stream>>>(h2b, m2, coef, 8388608L);

    // ---- block 3 ----
    conv_mfma<64, 512, 128, 2, 32, 16, 4, 2, 4, 2, 4, 2>
        <<<1024, 256, 0, stream>>>(h2b, w3ah, m3, h3a, zbuf);
    hipMemsetAsync(stats, 0, 4096, stream);
    bn_stats_v<512><<<128, 256, 0, stream>>>(h3a, 8388608L, stats);
    bn_coef_kernel<<<1, 512, 0, stream>>>(stats, counts + 2, g3a, b3a, coef, 512);
    bn_apply_v<512, 9><<<512, 256, 0, stream>>>(h3a, m3, coef, 8388608L);

    conv_mfma<512, 512, 128, 1, 16, 16, 8, 3, 4, 2, 4, 2>
        <<<512, 256, 0, stream>>>(h3a, w3bh, m3, h3b, zbuf);
    hipMemsetAsync(stats, 0, 4096, stream);
    bn_stats_v<512><<<128, 256, 0, stream>>>(h3b, 8388608L, stats);
    bn_coef_kernel<<<1, 512, 0, stream>>>(stats, counts + 2, g3b, b3b, coef, 512);
    bn_apply_v<512, 9><<<512, 256, 0, stream>>>(h3b, m3, coef, 8388608L);

    // ---- pool + heads ----
    gpool_kernel<<<32, 256, 0, stream>>>(h3b, pooled);
    head_kernel<<<16, 256, 0, stream>>>(pooled, counts + 4, wm, bm, wv, bv, out);
}